// Round 11
// baseline (280.704 us; speedup 1.0000x reference)
//
#include <hip/hip_runtime.h>
#include <hip/hip_fp16.h>
#include <stdint.h>

#define N_NODES 50000
#define N_EDGES 800000
#define BCAP 64    // Poisson(16): P(deg>64) ~ 1e-22 — clamp is safe
#define NPART 782  // ceil(50000/64) dst-range partitions, 64 nodes each
#define NSUB 32    // 4 sub-lists per XCD per partition -> XCD-exclusive cursor lines
#define SCAP 128   // per-sub-list capacity: mean 32 -> huge margin

typedef _Float16 f16x8 __attribute__((ext_vector_type(8)));
typedef __attribute__((ext_vector_type(4))) float f32x4;

__device__ __forceinline__ unsigned short f2h(float f) {
    return __builtin_bit_cast(unsigned short, (_Float16)f);
}

// fp8 e4m3 with +2^-6 offset (inputs >= 0 post-relu): code is ALWAYS normal (c>=8),
// so decode is exactly linear in bits: f16 = (c<<7) + 0x2000. The +2^-6 telescopes
// to a per-node constant removed after reduction. v=0 roundtrips exactly.
__device__ __forceinline__ unsigned char f2fp8o(float v) {
    v = fminf(v, 440.f) + 0.015625f;
    unsigned int u = __builtin_bit_cast(unsigned int, v);
    u += 0x7FFFFu + ((u >> 20) & 1u);            // RNE to 3 mantissa bits
    return (unsigned char)((u >> 20) - 960u);    // ((exp-120)<<3)|mant3, 8..126
}

__device__ __forceinline__ void load_lds16(const void* g, void* l) {
    __builtin_amdgcn_global_load_lds(
        (const __attribute__((address_space(1))) void*)(uintptr_t)g,
        (__attribute__((address_space(3))) void*)(unsigned int)(uintptr_t)l,
        16, 0, 0);
}

// ---------------- build pass A: append edges into (partition, XCD-local sub) lists --
// R18 mechanism: R15's append wrote 42.5MB HBM for 6.4MB of payload (6.6x write
// amplification at 1.0TB/s = the whole 43.5us) — the same cursor line was dirtied
// in all 8 non-coherent XCD L2s and every copy wrote back.  Fix: sub-list index
// carries the REAL XCD id (s_getreg HW_REG_XCC_ID, HW-verified on gfx950 m09) ->
// each pcnt/pbuf line is written by exactly ONE XCD: one L2 copy, one writeback,
// L2-local atomics.  Mapping is locality-only (atomics are device-scope) so
// correctness never depends on it.  4 edges/thread = 4 independent atomic chains
// on 4 DISTINCT cursors ((e&3) sub-split).
__global__ __launch_bounds__(256) void part_append_k(
    const int* __restrict__ src, const int* __restrict__ dst,
    int* __restrict__ pcnt, unsigned int* __restrict__ pbuf, int nedges)
{
    unsigned xcc;
    asm("s_getreg_b32 %0, hwreg(HW_REG_XCC_ID)" : "=s"(xcc));
    const int sbase = (int)(xcc & 7) * 4;

    int t = blockIdx.x * 256 + threadIdx.x;
    int e0 = t * 4;                               // e0 % 4 == 0
    if (e0 >= nedges) return;
    int4 s4 = *(const int4*)(src + e0);
    int4 d4 = *(const int4*)(dst + e0);

    int c0 = (d4.x >> 6) * NSUB + sbase + 0;
    int c1 = (d4.y >> 6) * NSUB + sbase + 1;
    int c2 = (d4.z >> 6) * NSUB + sbase + 2;
    int c3 = (d4.w >> 6) * NSUB + sbase + 3;

    int p0 = atomicAdd(&pcnt[c0 * 16], 1);
    int p1 = atomicAdd(&pcnt[c1 * 16], 1);
    int p2 = atomicAdd(&pcnt[c2 * 16], 1);
    int p3 = atomicAdd(&pcnt[c3 * 16], 1);

    if (p0 < SCAP) pbuf[(size_t)c0 * SCAP + p0] = ((unsigned)(d4.x & 63) << 16) | (unsigned)s4.x;
    if (p1 < SCAP) pbuf[(size_t)c1 * SCAP + p1] = ((unsigned)(d4.y & 63) << 16) | (unsigned)s4.y;
    if (p2 < SCAP) pbuf[(size_t)c2 * SCAP + p2] = ((unsigned)(d4.z & 63) << 16) | (unsigned)s4.z;
    if (p3 < SCAP) pbuf[(size_t)c3 * SCAP + p3] = ((unsigned)(d4.w & 63) << 16) | (unsigned)s4.w;
}

// ---------------- build pass B: per-partition local bucket fill (LDS counters) --------
// 4 waves scan the 32 sub-lists (8 each; n per sub ~32).
__global__ __launch_bounds__(256) void part_bucket_k(
    const int* __restrict__ pcnt, const unsigned int* __restrict__ pbuf,
    int* __restrict__ bucket, int* __restrict__ degtot, float* __restrict__ invdeg)
{
    __shared__ int lcnt[64];
    int part = blockIdx.x, tid = threadIdx.x;
    int wv = tid >> 6, lane = tid & 63;
    if (tid < 64) lcnt[tid] = 0;
    __syncthreads();
#pragma unroll
    for (int sub = wv; sub < NSUB; sub += 4) {
        int cidx = part * NSUB + sub;
        int n = pcnt[cidx * 16];
        if (n > SCAP) n = SCAP;
        const unsigned int* pb = pbuf + (size_t)cidx * SCAP;
        for (int i = lane; i < n; i += 64) {
            unsigned int en = pb[i];
            int dlow = (int)(en >> 16), s = (int)(en & 0xFFFFu);
            int p = atomicAdd(&lcnt[dlow], 1);
            if (p < BCAP) bucket[(size_t)(part * 64 + dlow) * BCAP + p] = s;
        }
    }
    __syncthreads();
    if (tid < 64) {
        int node = part * 64 + tid;
        if (node < N_NODES) {
            int c = lcnt[tid];
            degtot[node] = (c > BCAP) ? BCAP : c;
            invdeg[node] = 1.0f / (float)(c > 1 ? c : 1);
        }
    }
}

// ---------------- converts (f16 tables) ----------------
__global__ __launch_bounds__(256) void cvt_x_k(
    const float* __restrict__ x, unsigned short* __restrict__ dst)
{
    int tid = blockIdx.x * 256 + threadIdx.x;  // one per 4 floats
    if (tid >= N_NODES * 32) return;
    int row = tid >> 5, c = (tid & 31) * 4;
    float4 v = *(const float4*)(x + (size_t)row * 128 + c);
    ushort4 o;
    o.x = f2h(v.x); o.y = f2h(v.y); o.z = f2h(v.z); o.w = f2h(v.w);
    *(ushort4*)(dst + (size_t)row * 256 + 128 + c) = o;
}

__global__ __launch_bounds__(256) void cvt_w_k(
    const float* __restrict__ wl, const float* __restrict__ wr,
    unsigned short* __restrict__ dst, int Keach)
{
    int tid = blockIdx.x * 256 + threadIdx.x;
    if (tid >= 256 * 2 * Keach) return;
    int n = tid / (2 * Keach), k = tid - n * 2 * Keach;
    float v = (k < Keach) ? wl[(size_t)n * Keach + k]
                          : wr[(size_t)n * Keach + (k - Keach)];
    dst[tid] = f2h(v);
}

// ---------------- layer-1 aggregation: f16 gather, packed-f16 accumulate ------------
// (R14 form: 1 node/wave.  R17's 2-node/wave variant measured neutral with higher
// VGPR — reverted to the simpler best-measured config.)
__device__ __forceinline__ void acch4(__half2* a, uint4 u) {
    a[0] = __hadd2(a[0], __builtin_bit_cast(__half2, u.x));
    a[1] = __hadd2(a[1], __builtin_bit_cast(__half2, u.y));
    a[2] = __hadd2(a[2], __builtin_bit_cast(__half2, u.z));
    a[3] = __hadd2(a[3], __builtin_bit_cast(__half2, u.w));
}

__global__ __launch_bounds__(256) void agg1_k(
    const unsigned short* __restrict__ feat,
    const int* __restrict__ bucket, const int* __restrict__ degtot,
    const float* __restrict__ invdeg,
    unsigned short* __restrict__ outmsg)
{
    int wv = threadIdx.x >> 6, lane = threadIdx.x & 63;
    int node = blockIdx.x * 4 + wv;
    if (node >= N_NODES) return;
    int deg = degtot[node];
    int idx0 = bucket[(size_t)node * BCAP + lane];
    const int sub = lane >> 4;
    const int col = lane & 15;

    __half2 acc[4] = {};
    auto rowp = [&](int s) { return (const uint4*)(feat + (size_t)s * 256 + col * 8); };

    int j = 0;
    for (; j + 16 <= deg; j += 16) {
        int s0 = __shfl(idx0, j + sub),     s1 = __shfl(idx0, j + 4 + sub);
        int s2 = __shfl(idx0, j + 8 + sub), s3 = __shfl(idx0, j + 12 + sub);
        uint4 u0 = *rowp(s0), u1 = *rowp(s1), u2 = *rowp(s2), u3 = *rowp(s3);
        acch4(acc, u0); acch4(acc, u1); acch4(acc, u2); acch4(acc, u3);
    }
    for (; j + 8 <= deg; j += 8) {
        int s0 = __shfl(idx0, j + sub), s1 = __shfl(idx0, j + 4 + sub);
        uint4 u0 = *rowp(s0), u1 = *rowp(s1);
        acch4(acc, u0); acch4(acc, u1);
    }
    for (; j + 4 <= deg; j += 4) {
        uint4 u0 = *rowp(__shfl(idx0, j + sub));
        acch4(acc, u0);
    }
    if (j < deg) {                      // wave-uniform guard (R3 lesson)
        int e = j + sub;
        int ec = (e < deg) ? e : (deg - 1);
        uint4 u0 = *rowp(__shfl(idx0, ec));
        if (e < deg) acch4(acc, u0);
    }
#pragma unroll
    for (int stride = 32; stride >= 16; stride >>= 1)
#pragma unroll
        for (int v = 0; v < 4; v++) {
            int t = __shfl_xor(__builtin_bit_cast(int, acc[v]), stride);
            acc[v] = __hadd2(acc[v], __builtin_bit_cast(__half2, t));
        }

    if (lane < 16) {
        float s = invdeg[node];
        unsigned int o[4];
#pragma unroll
        for (int v = 0; v < 4; v++) {
            float2 f = __half22float2(acc[v]);
            o[v] = (unsigned int)f2h(f.x * s) | ((unsigned int)f2h(f.y * s) << 16);
        }
        *(uint4*)(outmsg + (size_t)node * 256 + lane * 8) = make_uint4(o[0], o[1], o[2], o[3]);
    }
}

// ---------------- layer-2 aggregation: offset-fp8 gather, linear decode, pk_add -----
__device__ __forceinline__ void accf8pk(__half2* a, unsigned int w) {
    unsigned int ev = ((w & 0x00FF00FFu) << 7) + 0x20002000u;
    unsigned int od = ((w >> 1) & 0x7F807F80u) + 0x20002000u;
    a[0] = __hadd2(a[0], __builtin_bit_cast(__half2, ev));
    a[1] = __hadd2(a[1], __builtin_bit_cast(__half2, od));
}
__device__ __forceinline__ void accf8x16(__half2* a, uint4 u) {
    accf8pk(a + 0, u.x); accf8pk(a + 2, u.y); accf8pk(a + 4, u.z); accf8pk(a + 6, u.w);
}

__global__ __launch_bounds__(256) void agg2_k(
    const unsigned char* __restrict__ hf8,
    const int* __restrict__ bucket, const int* __restrict__ degtot,
    const float* __restrict__ invdeg,
    unsigned short* __restrict__ outmsg)
{
    int wv = threadIdx.x >> 6, lane = threadIdx.x & 63;
    int node = blockIdx.x * 4 + wv;
    if (node >= N_NODES) return;
    int deg = degtot[node];
    int idx0 = bucket[(size_t)node * BCAP + lane];
    const int sub = lane >> 4;
    const int col = lane & 15;

    __half2 acc[8] = {};
    auto rowp = [&](int s) { return (const uint4*)(hf8 + (size_t)s * 256 + col * 16); };

    int j = 0;
    for (; j + 16 <= deg; j += 16) {
        int s0 = __shfl(idx0, j + sub),     s1 = __shfl(idx0, j + 4 + sub);
        int s2 = __shfl(idx0, j + 8 + sub), s3 = __shfl(idx0, j + 12 + sub);
        uint4 u0 = *rowp(s0), u1 = *rowp(s1), u2 = *rowp(s2), u3 = *rowp(s3);
        accf8x16(acc, u0); accf8x16(acc, u1); accf8x16(acc, u2); accf8x16(acc, u3);
    }
    for (; j + 8 <= deg; j += 8) {
        int s0 = __shfl(idx0, j + sub), s1 = __shfl(idx0, j + 4 + sub);
        uint4 u0 = *rowp(s0), u1 = *rowp(s1);
        accf8x16(acc, u0); accf8x16(acc, u1);
    }
    for (; j + 4 <= deg; j += 4) {
        uint4 u0 = *rowp(__shfl(idx0, j + sub));
        accf8x16(acc, u0);
    }
    if (j < deg) {
        int e = j + sub;
        int ec = (e < deg) ? e : (deg - 1);
        uint4 u0 = *rowp(__shfl(idx0, ec));
        if (e < deg) accf8x16(acc, u0);
    }
#pragma unroll
    for (int stride = 32; stride >= 16; stride >>= 1)
#pragma unroll
        for (int v = 0; v < 8; v++) {
            int t = __shfl_xor(__builtin_bit_cast(int, acc[v]), stride);
            acc[v] = __hadd2(acc[v], __builtin_bit_cast(__half2, t));
        }

    if (lane < 16) {
        float s = invdeg[node];
        float bias = (deg > 0) ? 0.015625f : 0.0f;
        unsigned int o[8];
#pragma unroll
        for (int q = 0; q < 4; q++) {
            float2 ev = __half22float2(acc[2 * q]);
            float2 od = __half22float2(acc[2 * q + 1]);
            float d0 = ev.x * s - bias, d1 = od.x * s - bias;
            float d2 = ev.y * s - bias, d3 = od.y * s - bias;
            o[2 * q]     = (unsigned int)f2h(d0) | ((unsigned int)f2h(d1) << 16);
            o[2 * q + 1] = (unsigned int)f2h(d2) | ((unsigned int)f2h(d3) << 16);
        }
        unsigned short* wp = outmsg + (size_t)node * 512 + lane * 16;
        *(uint4*)(wp)     = make_uint4(o[0], o[1], o[2], o[3]);
        *(uint4*)(wp + 8) = make_uint4(o[4], o[5], o[6], o[7]);
    }
}

// ---------------- f16 MFMA GEMM (R14 exact — best measured total 277.8us) ----------
// 2x16KB double-buffer, __syncthreads per K-step, in-row XOR swizzle staging
// (conflicts 0, coalescing identical to R0, FETCH/WRITE at traffic floor).
// 7 schedule variants bracket this structure at 43±1us; frozen.
template <bool F16OUT, bool WRITE_FP8>
__global__ __launch_bounds__(256) void gemm_k(
    const unsigned short* __restrict__ A, const unsigned short* __restrict__ W,
    const float* __restrict__ bias, void* __restrict__ outp, int outStride,
    unsigned char* __restrict__ hf8, int M, int K)
{
    __shared__ __align__(16) char smem[2 * 16384];  // 32 KB: two 16KB tile buffers
    const int t = threadIdx.x;
    const int w = t >> 6, lane = t & 63;
    const int quad = lane >> 4, l15 = lane & 15;
    const int row0 = blockIdx.x * 128;
    const int col0 = blockIdx.y * 128;
    const int niter = K >> 5;

    auto stage = [&](int buf, int ks) {
#pragma unroll
        for (int j = 0; j < 4; j++) {
            int call = w * 4 + j;        // 0..15, wave-uniform A/W split at 8
            int ci = call * 64 + lane;   // chunk id 0..1023
            const unsigned short* g;
            if (call < 8) {              // A chunks
                int rg = row0 + (ci >> 2);
                if (rg > M - 1) rg = M - 1;
                g = A + (size_t)rg * K + ks + (((ci & 3) ^ ((ci >> 3) & 3)) * 8);
            } else {                     // W chunks
                int c2 = ci - 512;
                g = W + (size_t)(col0 + (c2 >> 2)) * K + ks + (((c2 & 3) ^ ((c2 >> 3) & 3)) * 8);
            }
            load_lds16(g, smem + buf * 16384 + ci * 16);
        }
    };

    f32x4 acc[2][8] = {};

    stage(0, 0);
    __syncthreads();                     // tile 0 ready

    const int qs = (quad ^ ((l15 >> 1) & 3)) * 16;   // swizzled chunk byte offset

    for (int i = 0; i < niter; i++) {
        if (i + 1 < niter) stage((i + 1) & 1, (i + 1) << 5);   // async prefetch

        const char* base = smem + (i & 1) * 16384;
        const char* Ab = base + (w * 32 + l15) * 64 + qs;
        const char* Wb = base + 8192 + l15 * 64 + qs;
        f16x8 af0 = *(const f16x8*)(Ab);
        f16x8 af1 = *(const f16x8*)(Ab + 1024);
#pragma unroll
        for (int tt = 0; tt < 8; tt++) {
            f16x8 bfr = *(const f16x8*)(Wb + tt * 1024);
            acc[0][tt] = __builtin_amdgcn_mfma_f32_16x16x32_f16(af0, bfr, acc[0][tt], 0, 0, 0);
            acc[1][tt] = __builtin_amdgcn_mfma_f32_16x16x32_f16(af1, bfr, acc[1][tt], 0, 0, 0);
        }
        __syncthreads();                 // drains prefetch; frees buf (i&1) for iter i+1
    }

#pragma unroll
    for (int g = 0; g < 2; g++) {
#pragma unroll
        for (int tt = 0; tt < 8; tt++) {
            int col = col0 + tt * 16 + l15;
            float bv = bias[col];
#pragma unroll
            for (int i = 0; i < 4; i++) {
                int row = row0 + w * 32 + g * 16 + quad * 4 + i;  // C/D: col=lane&15, row=quad*4+reg
                if (row < M) {
                    float v = fmaxf(acc[g][tt][i] + bv, 0.f);
                    size_t off = (size_t)row * outStride + col;
                    if constexpr (F16OUT) ((unsigned short*)outp)[off] = f2h(v);
                    else                  ((float*)outp)[off] = v;
                    if constexpr (WRITE_FP8) hf8[(size_t)row * 256 + col] = f2fp8o(v);
                }
            }
        }
    }
}

extern "C" void kernel_launch(void* const* d_in, const int* in_sizes, int n_in,
                              void* d_out, int out_size, void* d_ws, size_t ws_size,
                              hipStream_t stream)
{
    const float* x   = (const float*)d_in[0];
    const int*   ei  = (const int*)d_in[1];
    const float* wl1 = (const float*)d_in[2];
    const float* bl1 = (const float*)d_in[3];
    const float* wr1 = (const float*)d_in[4];
    const float* wl2 = (const float*)d_in[5];
    const float* bl2 = (const float*)d_in[6];
    const float* wr2 = (const float*)d_in[7];
    float* out = (float*)d_out;
    const int* src = ei;
    const int* dst = ei + N_EDGES;

    char* ws = (char*)d_ws;
    size_t off = 0;
    auto alloc = [&](size_t bytes) -> void* {
        void* p = ws + off;
        off = (off + bytes + 255) & ~(size_t)255;
        return p;
    };
    int*            pcnt   = (int*)           alloc((size_t)NPART * NSUB * 16 * 4);
    unsigned int*   pbuf   = (unsigned int*)  alloc((size_t)NPART * NSUB * SCAP * 4);
    int*            bucket = (int*)           alloc((size_t)NPART * 64 * BCAP * 4);
    int*            degtot = (int*)           alloc((size_t)N_NODES * 4);
    float*          invdeg = (float*)         alloc((size_t)N_NODES * 4);
    unsigned short* Acat1  = (unsigned short*)alloc((size_t)N_NODES * 256 * 2);  // [msg1|x] f16
    unsigned short* Acat2  = (unsigned short*)alloc((size_t)N_NODES * 512 * 2);  // [msg2|h] f16
    unsigned char*  hf8    = (unsigned char*) alloc((size_t)N_NODES * 256);      // h fp8+offset
    unsigned short* Wcat1  = (unsigned short*)alloc((size_t)256 * 256 * 2);
    unsigned short* Wcat2  = (unsigned short*)alloc((size_t)256 * 512 * 2);

    hipMemsetAsync(pcnt, 0, (size_t)NPART * NSUB * 16 * 4, stream);
    part_append_k<<<(N_EDGES / 4 + 255) / 256, 256, 0, stream>>>(src, dst, pcnt, pbuf, N_EDGES);
    part_bucket_k<<<NPART, 256, 0, stream>>>(pcnt, pbuf, bucket, degtot, invdeg);

    cvt_x_k<<<(N_NODES * 32 + 255) / 256, 256, 0, stream>>>(x, Acat1);
    cvt_w_k<<<(256 * 256 + 255) / 256, 256, 0, stream>>>(wl1, wr1, Wcat1, 128);
    cvt_w_k<<<(256 * 512 + 255) / 256, 256, 0, stream>>>(wl2, wr2, Wcat2, 256);

    // Layer 1: agg x_f16 -> msg1; h = relu(Acat1 @ Wcat1^T + b) -> Acat2 right half (f16) + hf8
    agg1_k<<<(N_NODES + 3) / 4, 256, 0, stream>>>(
        Acat1 + 128, bucket, degtot, invdeg, Acat1);
    gemm_k<true, true><<<dim3((N_NODES + 127) / 128, 2), 256, 0, stream>>>(
        Acat1, Wcat1, bl1, (void*)(Acat2 + 256), 512, hf8, N_NODES, 256);

    // Layer 2: agg hf8 -> msg2; out = relu(Acat2 @ Wcat2^T + b) fp32
    agg2_k<<<(N_NODES + 3) / 4, 256, 0, stream>>>(
        hf8, bucket, degtot, invdeg, Acat2);
    gemm_k<false, false><<<dim3((N_NODES + 127) / 128, 2), 256, 0, stream>>>(
        Acat2, Wcat2, bl2, (void*)out, 256, nullptr, N_NODES, 512);
}

// Round 12
// 270.223 us; speedup vs baseline: 1.0388x; 1.0388x over previous
//
#include <hip/hip_runtime.h>
#include <hip/hip_fp16.h>
#include <stdint.h>

#define N_NODES 50000
#define N_EDGES 800000
#define BCAP 64    // Poisson(16): P(deg>64) ~ 1e-22 — clamp is safe
#define NPART 782  // ceil(50000/64) dst-range partitions, 64 nodes each
#define NSUB 32    // 4 sub-lists per XCD per partition -> XCD-exclusive cursor lines
#define SCAP 128   // per-sub-list capacity: mean 32 -> huge margin

// prep_k fused-grid block ranges (append | cvt_x | cvt_w1 | cvt_w2)
#define NB_APPEND 782          // ceil(800000/4/256)
#define NB_CVTX   6250         // 50000*32/256
#define NB_CVTW1  256          // 256*256/256
#define NB_CVTW2  512          // 256*512/256

typedef _Float16 f16x8 __attribute__((ext_vector_type(8)));
typedef __attribute__((ext_vector_type(4))) float f32x4;

__device__ __forceinline__ unsigned short f2h(float f) {
    return __builtin_bit_cast(unsigned short, (_Float16)f);
}

// fp8 e4m3 with +2^-6 offset (inputs >= 0 post-relu): code is ALWAYS normal (c>=8),
// so decode is exactly linear in bits: f16 = (c<<7) + 0x2000. The +2^-6 telescopes
// to a per-node constant removed after reduction. v=0 roundtrips exactly.
__device__ __forceinline__ unsigned char f2fp8o(float v) {
    v = fminf(v, 440.f) + 0.015625f;
    unsigned int u = __builtin_bit_cast(unsigned int, v);
    u += 0x7FFFFu + ((u >> 20) & 1u);            // RNE to 3 mantissa bits
    return (unsigned char)((u >> 20) - 960u);    // ((exp-120)<<3)|mant3, 8..126
}

__device__ __forceinline__ void load_lds16(const void* g, void* l) {
    __builtin_amdgcn_global_load_lds(
        (const __attribute__((address_space(1))) void*)(uintptr_t)g,
        (__attribute__((address_space(3))) void*)(unsigned int)(uintptr_t)l,
        16, 0, 0);
}

// ---------------- fused prep: append ∥ cvt_x ∥ cvt_w1 ∥ cvt_w2 (R20) ---------------
// R19 post-mortem: six configs pinned at 278-281 total while every component change
// measured neutral — the unattacked block is the serial chain of independent prep
// kernels (4 launches, each with its own gap; append runs at VALUBusy 0.65% / 13%
// BW leaving the machine idle).  These four have NO mutual deps: fuse into one
// launch, block-range branched, bodies byte-identical.  Append blocks (782) first
// (the long pole); 7018 cvt blocks fill the idle slots underneath.
__global__ __launch_bounds__(256) void prep_k(
    const int* __restrict__ src, const int* __restrict__ dst,
    int* __restrict__ pcnt, unsigned int* __restrict__ pbuf,
    const float* __restrict__ x, unsigned short* __restrict__ xdst,
    const float* __restrict__ wl1, const float* __restrict__ wr1,
    unsigned short* __restrict__ w1dst,
    const float* __restrict__ wl2, const float* __restrict__ wr2,
    unsigned short* __restrict__ w2dst)
{
    int bid = blockIdx.x;
    if (bid < NB_APPEND) {
        // ---- build pass A: append edges into (partition, XCD-local sub) lists.
        // R18 mechanism: sub-list index carries the REAL XCD id (s_getreg
        // HW_REG_XCC_ID, HW-verified gfx950 m09) -> each pcnt/pbuf line is written
        // by ONE XCD: one L2 copy/writeback, L2-local atomics.  Mapping is
        // locality-only (atomics device-scope).  4 edges/thread = 4 independent
        // atomic chains on 4 DISTINCT cursors.
        unsigned xcc;
        asm("s_getreg_b32 %0, hwreg(HW_REG_XCC_ID)" : "=s"(xcc));
        const int sbase = (int)(xcc & 7) * 4;

        int t = bid * 256 + threadIdx.x;
        int e0 = t * 4;
        if (e0 >= N_EDGES) return;
        int4 s4 = *(const int4*)(src + e0);
        int4 d4 = *(const int4*)(dst + e0);

        int c0 = (d4.x >> 6) * NSUB + sbase + 0;
        int c1 = (d4.y >> 6) * NSUB + sbase + 1;
        int c2 = (d4.z >> 6) * NSUB + sbase + 2;
        int c3 = (d4.w >> 6) * NSUB + sbase + 3;

        int p0 = atomicAdd(&pcnt[c0 * 16], 1);
        int p1 = atomicAdd(&pcnt[c1 * 16], 1);
        int p2 = atomicAdd(&pcnt[c2 * 16], 1);
        int p3 = atomicAdd(&pcnt[c3 * 16], 1);

        if (p0 < SCAP) pbuf[(size_t)c0 * SCAP + p0] = ((unsigned)(d4.x & 63) << 16) | (unsigned)s4.x;
        if (p1 < SCAP) pbuf[(size_t)c1 * SCAP + p1] = ((unsigned)(d4.y & 63) << 16) | (unsigned)s4.y;
        if (p2 < SCAP) pbuf[(size_t)c2 * SCAP + p2] = ((unsigned)(d4.z & 63) << 16) | (unsigned)s4.z;
        if (p3 < SCAP) pbuf[(size_t)c3 * SCAP + p3] = ((unsigned)(d4.w & 63) << 16) | (unsigned)s4.w;
    } else if (bid < NB_APPEND + NB_CVTX) {
        // ---- cvt_x: x f32 -> f16 into Acat1 right half (one thread per 4 floats)
        int tid = (bid - NB_APPEND) * 256 + threadIdx.x;
        int row = tid >> 5, c = (tid & 31) * 4;
        float4 v = *(const float4*)(x + (size_t)row * 128 + c);
        ushort4 o;
        o.x = f2h(v.x); o.y = f2h(v.y); o.z = f2h(v.z); o.w = f2h(v.w);
        *(ushort4*)(xdst + (size_t)row * 256 + 128 + c) = o;
    } else if (bid < NB_APPEND + NB_CVTX + NB_CVTW1) {
        // ---- cvt_w1: [wl1|wr1] -> f16, Keach=128
        int tid = (bid - NB_APPEND - NB_CVTX) * 256 + threadIdx.x;
        int n = tid >> 8, k = tid & 255;
        float v = (k < 128) ? wl1[(size_t)n * 128 + k]
                            : wr1[(size_t)n * 128 + (k - 128)];
        w1dst[tid] = f2h(v);
    } else {
        // ---- cvt_w2: [wl2|wr2] -> f16, Keach=256
        int tid = (bid - NB_APPEND - NB_CVTX - NB_CVTW1) * 256 + threadIdx.x;
        int n = tid >> 9, k = tid & 511;
        float v = (k < 256) ? wl2[(size_t)n * 256 + k]
                            : wr2[(size_t)n * 256 + (k - 256)];
        w2dst[tid] = f2h(v);
    }
}

// ---------------- build pass B: per-partition local bucket fill (LDS counters) --------
// 4 waves scan the 32 sub-lists (8 each; n per sub ~32).
__global__ __launch_bounds__(256) void part_bucket_k(
    const int* __restrict__ pcnt, const unsigned int* __restrict__ pbuf,
    int* __restrict__ bucket, int* __restrict__ degtot, float* __restrict__ invdeg)
{
    __shared__ int lcnt[64];
    int part = blockIdx.x, tid = threadIdx.x;
    int wv = tid >> 6, lane = tid & 63;
    if (tid < 64) lcnt[tid] = 0;
    __syncthreads();
#pragma unroll
    for (int sub = wv; sub < NSUB; sub += 4) {
        int cidx = part * NSUB + sub;
        int n = pcnt[cidx * 16];
        if (n > SCAP) n = SCAP;
        const unsigned int* pb = pbuf + (size_t)cidx * SCAP;
        for (int i = lane; i < n; i += 64) {
            unsigned int en = pb[i];
            int dlow = (int)(en >> 16), s = (int)(en & 0xFFFFu);
            int p = atomicAdd(&lcnt[dlow], 1);
            if (p < BCAP) bucket[(size_t)(part * 64 + dlow) * BCAP + p] = s;
        }
    }
    __syncthreads();
    if (tid < 64) {
        int node = part * 64 + tid;
        if (node < N_NODES) {
            int c = lcnt[tid];
            degtot[node] = (c > BCAP) ? BCAP : c;
            invdeg[node] = 1.0f / (float)(c > 1 ? c : 1);
        }
    }
}

// ---------------- layer-1 aggregation: f16 gather, packed-f16 accumulate ------------
__device__ __forceinline__ void acch4(__half2* a, uint4 u) {
    a[0] = __hadd2(a[0], __builtin_bit_cast(__half2, u.x));
    a[1] = __hadd2(a[1], __builtin_bit_cast(__half2, u.y));
    a[2] = __hadd2(a[2], __builtin_bit_cast(__half2, u.z));
    a[3] = __hadd2(a[3], __builtin_bit_cast(__half2, u.w));
}

__global__ __launch_bounds__(256) void agg1_k(
    const unsigned short* __restrict__ feat,
    const int* __restrict__ bucket, const int* __restrict__ degtot,
    const float* __restrict__ invdeg,
    unsigned short* __restrict__ outmsg)
{
    int wv = threadIdx.x >> 6, lane = threadIdx.x & 63;
    int node = blockIdx.x * 4 + wv;
    if (node >= N_NODES) return;
    int deg = degtot[node];
    int idx0 = bucket[(size_t)node * BCAP + lane];
    const int sub = lane >> 4;
    const int col = lane & 15;

    __half2 acc[4] = {};
    auto rowp = [&](int s) { return (const uint4*)(feat + (size_t)s * 256 + col * 8); };

    int j = 0;
    for (; j + 16 <= deg; j += 16) {
        int s0 = __shfl(idx0, j + sub),     s1 = __shfl(idx0, j + 4 + sub);
        int s2 = __shfl(idx0, j + 8 + sub), s3 = __shfl(idx0, j + 12 + sub);
        uint4 u0 = *rowp(s0), u1 = *rowp(s1), u2 = *rowp(s2), u3 = *rowp(s3);
        acch4(acc, u0); acch4(acc, u1); acch4(acc, u2); acch4(acc, u3);
    }
    for (; j + 8 <= deg; j += 8) {
        int s0 = __shfl(idx0, j + sub), s1 = __shfl(idx0, j + 4 + sub);
        uint4 u0 = *rowp(s0), u1 = *rowp(s1);
        acch4(acc, u0); acch4(acc, u1);
    }
    for (; j + 4 <= deg; j += 4) {
        uint4 u0 = *rowp(__shfl(idx0, j + sub));
        acch4(acc, u0);
    }
    if (j < deg) {                      // wave-uniform guard (R3 lesson)
        int e = j + sub;
        int ec = (e < deg) ? e : (deg - 1);
        uint4 u0 = *rowp(__shfl(idx0, ec));
        if (e < deg) acch4(acc, u0);
    }
#pragma unroll
    for (int stride = 32; stride >= 16; stride >>= 1)
#pragma unroll
        for (int v = 0; v < 4; v++) {
            int t = __shfl_xor(__builtin_bit_cast(int, acc[v]), stride);
            acc[v] = __hadd2(acc[v], __builtin_bit_cast(__half2, t));
        }

    if (lane < 16) {
        float s = invdeg[node];
        unsigned int o[4];
#pragma unroll
        for (int v = 0; v < 4; v++) {
            float2 f = __half22float2(acc[v]);
            o[v] = (unsigned int)f2h(f.x * s) | ((unsigned int)f2h(f.y * s) << 16);
        }
        *(uint4*)(outmsg + (size_t)node * 256 + lane * 8) = make_uint4(o[0], o[1], o[2], o[3]);
    }
}

// ---------------- layer-2 aggregation: offset-fp8 gather, linear decode, pk_add -----
__device__ __forceinline__ void accf8pk(__half2* a, unsigned int w) {
    unsigned int ev = ((w & 0x00FF00FFu) << 7) + 0x20002000u;
    unsigned int od = ((w >> 1) & 0x7F807F80u) + 0x20002000u;
    a[0] = __hadd2(a[0], __builtin_bit_cast(__half2, ev));
    a[1] = __hadd2(a[1], __builtin_bit_cast(__half2, od));
}
__device__ __forceinline__ void accf8x16(__half2* a, uint4 u) {
    accf8pk(a + 0, u.x); accf8pk(a + 2, u.y); accf8pk(a + 4, u.z); accf8pk(a + 6, u.w);
}

__global__ __launch_bounds__(256) void agg2_k(
    const unsigned char* __restrict__ hf8,
    const int* __restrict__ bucket, const int* __restrict__ degtot,
    const float* __restrict__ invdeg,
    unsigned short* __restrict__ outmsg)
{
    int wv = threadIdx.x >> 6, lane = threadIdx.x & 63;
    int node = blockIdx.x * 4 + wv;
    if (node >= N_NODES) return;
    int deg = degtot[node];
    int idx0 = bucket[(size_t)node * BCAP + lane];
    const int sub = lane >> 4;
    const int col = lane & 15;

    __half2 acc[8] = {};
    auto rowp = [&](int s) { return (const uint4*)(hf8 + (size_t)s * 256 + col * 16); };

    int j = 0;
    for (; j + 16 <= deg; j += 16) {
        int s0 = __shfl(idx0, j + sub),     s1 = __shfl(idx0, j + 4 + sub);
        int s2 = __shfl(idx0, j + 8 + sub), s3 = __shfl(idx0, j + 12 + sub);
        uint4 u0 = *rowp(s0), u1 = *rowp(s1), u2 = *rowp(s2), u3 = *rowp(s3);
        accf8x16(acc, u0); accf8x16(acc, u1); accf8x16(acc, u2); accf8x16(acc, u3);
    }
    for (; j + 8 <= deg; j += 8) {
        int s0 = __shfl(idx0, j + sub), s1 = __shfl(idx0, j + 4 + sub);
        uint4 u0 = *rowp(s0), u1 = *rowp(s1);
        accf8x16(acc, u0); accf8x16(acc, u1);
    }
    for (; j + 4 <= deg; j += 4) {
        uint4 u0 = *rowp(__shfl(idx0, j + sub));
        accf8x16(acc, u0);
    }
    if (j < deg) {
        int e = j + sub;
        int ec = (e < deg) ? e : (deg - 1);
        uint4 u0 = *rowp(__shfl(idx0, ec));
        if (e < deg) accf8x16(acc, u0);
    }
#pragma unroll
    for (int stride = 32; stride >= 16; stride >>= 1)
#pragma unroll
        for (int v = 0; v < 8; v++) {
            int t = __shfl_xor(__builtin_bit_cast(int, acc[v]), stride);
            acc[v] = __hadd2(acc[v], __builtin_bit_cast(__half2, t));
        }

    if (lane < 16) {
        float s = invdeg[node];
        float bias = (deg > 0) ? 0.015625f : 0.0f;
        unsigned int o[8];
#pragma unroll
        for (int q = 0; q < 4; q++) {
            float2 ev = __half22float2(acc[2 * q]);
            float2 od = __half22float2(acc[2 * q + 1]);
            float d0 = ev.x * s - bias, d1 = od.x * s - bias;
            float d2 = ev.y * s - bias, d3 = od.y * s - bias;
            o[2 * q]     = (unsigned int)f2h(d0) | ((unsigned int)f2h(d1) << 16);
            o[2 * q + 1] = (unsigned int)f2h(d2) | ((unsigned int)f2h(d3) << 16);
        }
        unsigned short* wp = outmsg + (size_t)node * 512 + lane * 16;
        *(uint4*)(wp)     = make_uint4(o[0], o[1], o[2], o[3]);
        *(uint4*)(wp + 8) = make_uint4(o[4], o[5], o[6], o[7]);
    }
}

// ---------------- f16 MFMA GEMM (R14 exact — best measured total 277.8us) ----------
// 2x16KB double-buffer, __syncthreads per K-step, in-row XOR swizzle staging
// (conflicts 0, coalescing identical to R0, FETCH/WRITE at traffic floor).
// 7 schedule variants bracket this structure at 43±1us; frozen.
template <bool F16OUT, bool WRITE_FP8>
__global__ __launch_bounds__(256) void gemm_k(
    const unsigned short* __restrict__ A, const unsigned short* __restrict__ W,
    const float* __restrict__ bias, void* __restrict__ outp, int outStride,
    unsigned char* __restrict__ hf8, int M, int K)
{
    __shared__ __align__(16) char smem[2 * 16384];  // 32 KB: two 16KB tile buffers
    const int t = threadIdx.x;
    const int w = t >> 6, lane = t & 63;
    const int quad = lane >> 4, l15 = lane & 15;
    const int row0 = blockIdx.x * 128;
    const int col0 = blockIdx.y * 128;
    const int niter = K >> 5;

    auto stage = [&](int buf, int ks) {
#pragma unroll
        for (int j = 0; j < 4; j++) {
            int call = w * 4 + j;        // 0..15, wave-uniform A/W split at 8
            int ci = call * 64 + lane;   // chunk id 0..1023
            const unsigned short* g;
            if (call < 8) {              // A chunks
                int rg = row0 + (ci >> 2);
                if (rg > M - 1) rg = M - 1;
                g = A + (size_t)rg * K + ks + (((ci & 3) ^ ((ci >> 3) & 3)) * 8);
            } else {                     // W chunks
                int c2 = ci - 512;
                g = W + (size_t)(col0 + (c2 >> 2)) * K + ks + (((c2 & 3) ^ ((c2 >> 3) & 3)) * 8);
            }
            load_lds16(g, smem + buf * 16384 + ci * 16);
        }
    };

    f32x4 acc[2][8] = {};

    stage(0, 0);
    __syncthreads();                     // tile 0 ready

    const int qs = (quad ^ ((l15 >> 1) & 3)) * 16;   // swizzled chunk byte offset

    for (int i = 0; i < niter; i++) {
        if (i + 1 < niter) stage((i + 1) & 1, (i + 1) << 5);   // async prefetch

        const char* base = smem + (i & 1) * 16384;
        const char* Ab = base + (w * 32 + l15) * 64 + qs;
        const char* Wb = base + 8192 + l15 * 64 + qs;
        f16x8 af0 = *(const f16x8*)(Ab);
        f16x8 af1 = *(const f16x8*)(Ab + 1024);
#pragma unroll
        for (int tt = 0; tt < 8; tt++) {
            f16x8 bfr = *(const f16x8*)(Wb + tt * 1024);
            acc[0][tt] = __builtin_amdgcn_mfma_f32_16x16x32_f16(af0, bfr, acc[0][tt], 0, 0, 0);
            acc[1][tt] = __builtin_amdgcn_mfma_f32_16x16x32_f16(af1, bfr, acc[1][tt], 0, 0, 0);
        }
        __syncthreads();                 // drains prefetch; frees buf (i&1) for iter i+1
    }

#pragma unroll
    for (int g = 0; g < 2; g++) {
#pragma unroll
        for (int tt = 0; tt < 8; tt++) {
            int col = col0 + tt * 16 + l15;
            float bv = bias[col];
#pragma unroll
            for (int i = 0; i < 4; i++) {
                int row = row0 + w * 32 + g * 16 + quad * 4 + i;  // C/D: col=lane&15, row=quad*4+reg
                if (row < M) {
                    float v = fmaxf(acc[g][tt][i] + bv, 0.f);
                    size_t off = (size_t)row * outStride + col;
                    if constexpr (F16OUT) ((unsigned short*)outp)[off] = f2h(v);
                    else                  ((float*)outp)[off] = v;
                    if constexpr (WRITE_FP8) hf8[(size_t)row * 256 + col] = f2fp8o(v);
                }
            }
        }
    }
}

extern "C" void kernel_launch(void* const* d_in, const int* in_sizes, int n_in,
                              void* d_out, int out_size, void* d_ws, size_t ws_size,
                              hipStream_t stream)
{
    const float* x   = (const float*)d_in[0];
    const int*   ei  = (const int*)d_in[1];
    const float* wl1 = (const float*)d_in[2];
    const float* bl1 = (const float*)d_in[3];
    const float* wr1 = (const float*)d_in[4];
    const float* wl2 = (const float*)d_in[5];
    const float* bl2 = (const float*)d_in[6];
    const float* wr2 = (const float*)d_in[7];
    float* out = (float*)d_out;
    const int* src = ei;
    const int* dst = ei + N_EDGES;

    char* ws = (char*)d_ws;
    size_t off = 0;
    auto alloc = [&](size_t bytes) -> void* {
        void* p = ws + off;
        off = (off + bytes + 255) & ~(size_t)255;
        return p;
    };
    int*            pcnt   = (int*)           alloc((size_t)NPART * NSUB * 16 * 4);
    unsigned int*   pbuf   = (unsigned int*)  alloc((size_t)NPART * NSUB * SCAP * 4);
    int*            bucket = (int*)           alloc((size_t)NPART * 64 * BCAP * 4);
    int*            degtot = (int*)           alloc((size_t)N_NODES * 4);
    float*          invdeg = (float*)         alloc((size_t)N_NODES * 4);
    unsigned short* Acat1  = (unsigned short*)alloc((size_t)N_NODES * 256 * 2);  // [msg1|x] f16
    unsigned short* Acat2  = (unsigned short*)alloc((size_t)N_NODES * 512 * 2);  // [msg2|h] f16
    unsigned char*  hf8    = (unsigned char*) alloc((size_t)N_NODES * 256);      // h fp8+offset
    unsigned short* Wcat1  = (unsigned short*)alloc((size_t)256 * 256 * 2);
    unsigned short* Wcat2  = (unsigned short*)alloc((size_t)256 * 512 * 2);

    hipMemsetAsync(pcnt, 0, (size_t)NPART * NSUB * 16 * 4, stream);

    // Fused prep: append ∥ cvt_x ∥ cvt_w1 ∥ cvt_w2 (independent work, one launch)
    prep_k<<<NB_APPEND + NB_CVTX + NB_CVTW1 + NB_CVTW2, 256, 0, stream>>>(
        src, dst, pcnt, pbuf, x, Acat1, wl1, wr1, Wcat1, wl2, wr2, Wcat2);

    part_bucket_k<<<NPART, 256, 0, stream>>>(pcnt, pbuf, bucket, degtot, invdeg);

    // Layer 1: agg x_f16 -> msg1; h = relu(Acat1 @ Wcat1^T + b) -> Acat2 right half (f16) + hf8
    agg1_k<<<(N_NODES + 3) / 4, 256, 0, stream>>>(
        Acat1 + 128, bucket, degtot, invdeg, Acat1);
    gemm_k<true, true><<<dim3((N_NODES + 127) / 128, 2), 256, 0, stream>>>(
        Acat1, Wcat1, bl1, (void*)(Acat2 + 256), 512, hf8, N_NODES, 256);

    // Layer 2: agg hf8 -> msg2; out = relu(Acat2 @ Wcat2^T + b) fp32
    agg2_k<<<(N_NODES + 3) / 4, 256, 0, stream>>>(
        hf8, bucket, degtot, invdeg, Acat2);
    gemm_k<false, false><<<dim3((N_NODES + 127) / 128, 2), 256, 0, stream>>>(
        Acat2, Wcat2, bl2, (void*)out, 256, nullptr, N_NODES, 512);
}